// Round 3
// baseline (418.459 us; speedup 1.0000x reference)
//
#include <hip/hip_runtime.h>
#include <hip/hip_bf16.h>
#include <math.h>

typedef __hip_bfloat16 bf16;
typedef __attribute__((ext_vector_type(8))) short bf16x8;
typedef __attribute__((ext_vector_type(4))) float f32x4;

#define GPTR(p) ((const __attribute__((address_space(1))) void*)(p))
#define LPTR(p) ((__attribute__((address_space(3))) void*)(p))

// ---------------------------------------------------------------------------
// fp32 -> bf16 conversion, 4 elements/thread, n % 1024 == 0.
// ---------------------------------------------------------------------------
__global__ __launch_bounds__(256) void cvt_f32_bf16(
    const float* __restrict__ in, bf16* __restrict__ out, int n)
{
  const int i = (blockIdx.x * 256 + threadIdx.x) * 4;
  if (i < n) {
    const float4 f = *(const float4*)(in + i);
    ushort4 u;
    u.x = __bfloat16_as_ushort(__float2bfloat16(f.x));
    u.y = __bfloat16_as_ushort(__float2bfloat16(f.y));
    u.z = __bfloat16_as_ushort(__float2bfloat16(f.z));
    u.w = __bfloat16_as_ushort(__float2bfloat16(f.w));
    *(ushort4*)(out + i) = u;
  }
}

// ---------------------------------------------------------------------------
// GEMM: C[M,N](bf16) = A[M,K](bf16,lda) * B[N,K]^T(bf16) + bias(fp32),
// optional exact-GELU, optional residual (RESID: 0 none, 1 fp32, 2 bf16).
// 128x128 tile, BK=64, 4 waves (2x2), 4x4 mfma_f32_16x16x32_bf16 per wave.
// global_load_lds width=16 staging (m97 structure, ref-checked in learn_hip).
// ---------------------------------------------------------------------------
template<int GELU, int RESID>
__global__ __launch_bounds__(256) void gemm_bt(
    const bf16* __restrict__ A, int lda,
    const bf16* __restrict__ B,
    const float* __restrict__ bias,
    const void* __restrict__ Rv, int ldr,
    bf16* __restrict__ C, int ldc,
    int M, int N, int K)
{
  __shared__ __align__(16) bf16 As[128 * 64];
  __shared__ __align__(16) bf16 Bs[128 * 64];

  const int t    = threadIdx.x;
  const int lane = t & 63;
  const int w    = t >> 6;
  const int wm   = w >> 1;
  const int wn   = w & 1;
  const int lr   = lane & 15;       // fragment row (A) / col (B,C)
  const int lq   = lane >> 4;       // quad 0..3
  const int m0   = blockIdx.y * 128;
  const int n0   = blockIdx.x * 128;

  f32x4 acc[4][4];
  #pragma unroll
  for (int mi = 0; mi < 4; ++mi)
    #pragma unroll
    for (int ni = 0; ni < 4; ++ni)
      acc[mi][ni] = (f32x4){0.f, 0.f, 0.f, 0.f};

  const int wbase = (t & ~63) * 8;  // wave-uniform LDS element base

  for (int k0 = 0; k0 < K; k0 += 64) {
    #pragma unroll
    for (int it = 0; it < 4; ++it) {
      const int c   = it * 256 + t;
      const int row = c >> 3;
      const int col = (c & 7) << 3;
      const bf16* ga = A + (size_t)(m0 + row) * lda + k0 + col;
      const bf16* gb = B + (size_t)(n0 + row) * K + k0 + col;
      __builtin_amdgcn_global_load_lds(GPTR(ga), LPTR(&As[it * 2048 + wbase]), 16, 0, 0);
      __builtin_amdgcn_global_load_lds(GPTR(gb), LPTR(&Bs[it * 2048 + wbase]), 16, 0, 0);
    }
    __syncthreads();

    #pragma unroll
    for (int ks = 0; ks < 2; ++ks) {
      bf16x8 af[4], bfr[4];
      #pragma unroll
      for (int mi = 0; mi < 4; ++mi)
        af[mi] = *(const bf16x8*)&As[(wm * 64 + mi * 16 + lr) * 64 + ks * 32 + lq * 8];
      #pragma unroll
      for (int ni = 0; ni < 4; ++ni)
        bfr[ni] = *(const bf16x8*)&Bs[(wn * 64 + ni * 16 + lr) * 64 + ks * 32 + lq * 8];
      #pragma unroll
      for (int mi = 0; mi < 4; ++mi)
        #pragma unroll
        for (int ni = 0; ni < 4; ++ni)
          acc[mi][ni] = __builtin_amdgcn_mfma_f32_16x16x32_bf16(af[mi], bfr[ni], acc[mi][ni], 0, 0, 0);
    }
    __syncthreads();
  }

  // epilogue: C/D layout col=lane&15, row=quad*4+reg (m89-verified)
  #pragma unroll
  for (int ni = 0; ni < 4; ++ni) {
    const int col = n0 + wn * 64 + ni * 16 + lr;
    const float bv = bias[col];
    #pragma unroll
    for (int mi = 0; mi < 4; ++mi) {
      const int rowb = m0 + wm * 64 + mi * 16 + lq * 4;
      #pragma unroll
      for (int i = 0; i < 4; ++i) {
        float v = acc[mi][ni][i] + bv;
        if (GELU) v = 0.5f * v * (1.0f + erff(v * 0.70710678118654752f));
        if (RESID == 1) v += ((const float*)Rv)[(size_t)(rowb + i) * ldr + col];
        if (RESID == 2) v += __bfloat162float(((const bf16*)Rv)[(size_t)(rowb + i) * ldr + col]);
        C[(size_t)(rowb + i) * ldc + col] = __float2bfloat16(v);
      }
    }
  }
}

// ---------------------------------------------------------------------------
// Window-5 causal attention, IN-PLACE into the q-columns of qkv.
// One wave per (token, head); lane = dim (hd=64). qkv row: [q(1024)|k|v].
// ---------------------------------------------------------------------------
__global__ __launch_bounds__(256) void attn_win(bf16* __restrict__ qkv)
{
  const int wid  = blockIdx.x * 4 + (threadIdx.x >> 6);
  const int lane = threadIdx.x & 63;
  const int h    = wid & 15;
  const int tk   = wid >> 4;        // flat token 0..4095
  const int s    = tk & 2047;       // position within sequence (S=2048)

  const size_t base = (size_t)tk * 3072;
  const float q = __bfloat162float(qkv[base + h * 64 + lane]);

  const int W = (s + 1 < 5) ? (s + 1) : 5;
  float sc[5];
  for (int wj = 0; wj < W; ++wj) {
    const int off = W - 1 - wj;                     // key index j = s - off
    const size_t kb = base - (size_t)off * 3072 + 1024 + h * 64;
    float p = q * __bfloat162float(qkv[kb + lane]);
    #pragma unroll
    for (int d = 1; d < 64; d <<= 1) p += __shfl_xor(p, d);
    sc[wj] = p * 0.125f;                            // 1/sqrt(64)
  }
  float mx = sc[0];
  for (int wj = 1; wj < W; ++wj) mx = fmaxf(mx, sc[wj]);
  float pr[5], sum = 0.f;
  for (int wj = 0; wj < W; ++wj) { pr[wj] = expf(sc[wj] - mx); sum += pr[wj]; }
  const float inv = 1.f / sum;
  float o = 0.f;
  for (int wj = 0; wj < W; ++wj) {
    const int off = W - 1 - wj;
    const size_t vb = base - (size_t)off * 3072 + 2048 + h * 64;
    o += pr[wj] * __bfloat162float(qkv[vb + lane]);
  }
  qkv[base + h * 64 + lane] = __float2bfloat16(o * inv);
}

// ---------------------------------------------------------------------------
// LayerNorm over dim=1024: out = LN(in)*g + b. in = bf16 (strided row ld),
// g/b fp32, out bf16 (OUTF32=0) or fp32 (OUTF32=1). One wave per token.
// ---------------------------------------------------------------------------
template<int OUTF32>
__global__ __launch_bounds__(256) void ln_s(
    const bf16* __restrict__ in, int ld,
    const float* __restrict__ g, const float* __restrict__ bt,
    void* __restrict__ outv)
{
  const int tk   = blockIdx.x * 4 + (threadIdx.x >> 6);
  const int lane = threadIdx.x & 63;
  const size_t bi = (size_t)tk * ld;
  const size_t bo = (size_t)tk * 1024;

  float v[16];
  float sum = 0.f;
  #pragma unroll
  for (int i = 0; i < 16; ++i) {
    const float t = __bfloat162float(in[bi + i * 64 + lane]);
    v[i] = t;
    sum += t;
  }
  #pragma unroll
  for (int d = 1; d < 64; d <<= 1) sum += __shfl_xor(sum, d);
  const float mu = sum * (1.f / 1024.f);

  float sq = 0.f;
  #pragma unroll
  for (int i = 0; i < 16; ++i) { const float dv = v[i] - mu; sq += dv * dv; }
  #pragma unroll
  for (int d = 1; d < 64; d <<= 1) sq += __shfl_xor(sq, d);
  const float rstd = rsqrtf(sq * (1.f / 1024.f) + 1e-5f);

  #pragma unroll
  for (int i = 0; i < 16; ++i) {
    const int e = i * 64 + lane;
    const float o = (v[i] - mu) * rstd * g[e] + bt[e];
    if (OUTF32) ((float*)outv)[bo + e] = o;
    else        ((bf16*)outv)[bo + e] = __float2bfloat16(o);
  }
}

// ---------------------------------------------------------------------------
// Inputs are FLOAT32 (per reference; threshold arithmetic proves no bf16 in
// dataset). Convert MFMA operands to bf16 in ws; epilogue scalars stay fp32.
// WS layout (bytes, 72 MB total):
//   0        : qkv [4096,3072] bf16 (25.2 MB) -> later h [4096,4096] (33.6 MB)
//   33554432 : x_b [4096,1024] bf16            -> later pre-LN2 sum
//   41943040 : x1_b [4096,1024] bf16
//   50331648 : w_in_b  [3072,1024] bf16
//   56623104 : w_out_b [1024,1024] bf16
//   58720256 : w1_b    [4096,1024] bf16
//   67108864 : w2_b    [1024,4096] bf16
// ---------------------------------------------------------------------------
extern "C" void kernel_launch(void* const* d_in, const int* in_sizes, int n_in,
                              void* d_out, int out_size, void* d_ws, size_t ws_size,
                              hipStream_t stream)
{
  const float* x     = (const float*)d_in[0];
  const float* w_in  = (const float*)d_in[1];
  const float* b_in  = (const float*)d_in[2];
  const float* w_out = (const float*)d_in[3];
  const float* b_out = (const float*)d_in[4];
  const float* ln1_g = (const float*)d_in[5];
  const float* ln1_b = (const float*)d_in[6];
  const float* ln2_g = (const float*)d_in[7];
  const float* ln2_b = (const float*)d_in[8];
  const float* w1    = (const float*)d_in[9];
  const float* b1    = (const float*)d_in[10];
  const float* w2    = (const float*)d_in[11];
  const float* b2    = (const float*)d_in[12];
  float* out = (float*)d_out;

  char* ws = (char*)d_ws;
  bf16* qkv     = (bf16*)(ws);                      // also h in phase 2
  bf16* h       = (bf16*)(ws);
  bf16* x_b     = (bf16*)(ws + 33554432);           // also pre-LN2 sum
  bf16* x1_b    = (bf16*)(ws + 41943040);
  bf16* w_in_b  = (bf16*)(ws + 50331648);
  bf16* w_out_b = (bf16*)(ws + 56623104);
  bf16* w1_b    = (bf16*)(ws + 58720256);
  bf16* w2_b    = (bf16*)(ws + 67108864);

  const dim3 blk(256);

  // 0) fp32 -> bf16 for MFMA operands
  cvt_f32_bf16<<<dim3(4096), blk, 0, stream>>>(x,     x_b,     4194304);
  cvt_f32_bf16<<<dim3(3072), blk, 0, stream>>>(w_in,  w_in_b,  3145728);
  cvt_f32_bf16<<<dim3(1024), blk, 0, stream>>>(w_out, w_out_b, 1048576);
  cvt_f32_bf16<<<dim3(4096), blk, 0, stream>>>(w1,    w1_b,    4194304);
  cvt_f32_bf16<<<dim3(4096), blk, 0, stream>>>(w2,    w2_b,    4194304);

  // 1) qkv = x @ w_in^T + b_in                      [4096,3072]
  gemm_bt<0,0><<<dim3(24, 32), blk, 0, stream>>>(x_b, 1024, w_in_b, b_in,
                                                 nullptr, 0, qkv, 3072,
                                                 4096, 3072, 1024);
  // 2) windowed causal attention, in-place into q-cols
  attn_win<<<dim3(16384), blk, 0, stream>>>(qkv);
  // 3) v-cols = x(fp32) + attn @ w_out^T + b_out    [4096,1024]
  gemm_bt<0,1><<<dim3(8, 32), blk, 0, stream>>>(qkv, 3072, w_out_b, b_out,
                                                x, 1024, qkv + 2048, 3072,
                                                4096, 1024, 1024);
  // 4) x1_b = LN(v-cols)
  ln_s<0><<<dim3(1024), blk, 0, stream>>>(qkv + 2048, 3072, ln1_g, ln1_b, x1_b);
  // 5) h = gelu(x1 @ w1^T + b1)                     [4096,4096]  (qkv dead)
  gemm_bt<1,0><<<dim3(32, 32), blk, 0, stream>>>(x1_b, 1024, w1_b, b1,
                                                 nullptr, 0, h, 4096,
                                                 4096, 4096, 1024);
  // 6) x_b = x1(bf16 resid) + h @ w2^T + b2         [4096,1024]  (x_b dead)
  gemm_bt<0,2><<<dim3(8, 32), blk, 0, stream>>>(h, 4096, w2_b, b2,
                                                x1_b, 1024, x_b, 1024,
                                                4096, 1024, 4096);
  // 7) out(fp32) = LN(x_b)
  ln_s<1><<<dim3(1024), blk, 0, stream>>>(x_b, 1024, ln2_g, ln2_b, out);
}

// Round 4
// 351.063 us; speedup vs baseline: 1.1920x; 1.1920x over previous
//
#include <hip/hip_runtime.h>
#include <hip/hip_bf16.h>
#include <math.h>

typedef __hip_bfloat16 bf16;
typedef __attribute__((ext_vector_type(8))) short bf16x8;
typedef __attribute__((ext_vector_type(4))) float f32x4;

#define GPTR(p) ((const __attribute__((address_space(1))) void*)(p))
#define LPTR(p) ((__attribute__((address_space(3))) void*)(p))

// ---------------------------------------------------------------------------
// fp32 -> bf16 conversion, 4 elements/thread.
// ---------------------------------------------------------------------------
__global__ __launch_bounds__(256) void cvt_f32_bf16(
    const float* __restrict__ in, bf16* __restrict__ out, int n)
{
  const int i = (blockIdx.x * 256 + threadIdx.x) * 4;
  if (i < n) {
    const float4 f = *(const float4*)(in + i);
    ushort4 u;
    u.x = __bfloat16_as_ushort(__float2bfloat16(f.x));
    u.y = __bfloat16_as_ushort(__float2bfloat16(f.y));
    u.z = __bfloat16_as_ushort(__float2bfloat16(f.z));
    u.w = __bfloat16_as_ushort(__float2bfloat16(f.w));
    *(ushort4*)(out + i) = u;
  }
}

// ---------------------------------------------------------------------------
// GEMM: C[M,N](bf16) = A[M,K](lda) * B[N,K]^T(ldb) [+ bias(fp32)] with
// optional exact-GELU / residual epilogue and split-K via blockIdx.z:
// block kz handles K-range [kz*kchunk, (kz+1)*kchunk), writes partial to
// C + kz*czstride. LDS uses XOR chunk swizzle (chunk^= row&7): staging
// permutes the per-lane GLOBAL source chunk (keeps global_load_lds's
// uniform-base+lane*16 LDS constraint), fragment ds_read_b128 drops from
// 16-way to 2-way bank conflicts (2-way is free, m136).
// ---------------------------------------------------------------------------
template<int GELU, int RESID>   // RESID: 0 none, 1 fp32, 2 bf16
__global__ __launch_bounds__(256) void gemm_bt(
    const bf16* __restrict__ A, int lda,
    const bf16* __restrict__ B, int ldb,
    const float* __restrict__ bias,
    const void* __restrict__ Rv, int ldr,
    bf16* __restrict__ C, int ldc, long czstride,
    int M, int N, int kchunk)
{
  __shared__ __align__(16) bf16 As[128 * 64];
  __shared__ __align__(16) bf16 Bs[128 * 64];

  const int t    = threadIdx.x;
  const int lane = t & 63;
  const int w    = t >> 6;
  const int wm   = w >> 1;
  const int wn   = w & 1;
  const int lr   = lane & 15;       // fragment row (A) / col (B,C)
  const int lq   = lane >> 4;       // quad 0..3
  const int m0   = blockIdx.y * 128;
  const int n0   = blockIdx.x * 128;
  const int kz   = blockIdx.z;

  A += (size_t)kz * kchunk;
  B += (size_t)kz * kchunk;
  C += (size_t)kz * czstride;

  f32x4 acc[4][4];
  #pragma unroll
  for (int mi = 0; mi < 4; ++mi)
    #pragma unroll
    for (int ni = 0; ni < 4; ++ni)
      acc[mi][ni] = (f32x4){0.f, 0.f, 0.f, 0.f};

  const int wbase = (t & ~63) * 8;  // wave-uniform LDS element base

  for (int k0 = 0; k0 < kchunk; k0 += 64) {
    #pragma unroll
    for (int it = 0; it < 4; ++it) {
      const int c    = it * 256 + t;
      const int row  = c >> 3;
      const int csw  = ((c & 7) ^ (row & 7)) << 3;   // swizzled source chunk
      const bf16* ga = A + (size_t)(m0 + row) * lda + k0 + csw;
      const bf16* gb = B + (size_t)(n0 + row) * ldb + k0 + csw;
      __builtin_amdgcn_global_load_lds(GPTR(ga), LPTR(&As[it * 2048 + wbase]), 16, 0, 0);
      __builtin_amdgcn_global_load_lds(GPTR(gb), LPTR(&Bs[it * 2048 + wbase]), 16, 0, 0);
    }
    __syncthreads();

    #pragma unroll
    for (int ks = 0; ks < 2; ++ks) {
      const int swz = (((ks * 4 + lq) ^ (lr & 7)) << 3);  // swizzled read chunk
      bf16x8 af[4], bfr[4];
      #pragma unroll
      for (int mi = 0; mi < 4; ++mi)
        af[mi] = *(const bf16x8*)&As[(wm * 64 + mi * 16 + lr) * 64 + swz];
      #pragma unroll
      for (int ni = 0; ni < 4; ++ni)
        bfr[ni] = *(const bf16x8*)&Bs[(wn * 64 + ni * 16 + lr) * 64 + swz];
      #pragma unroll
      for (int mi = 0; mi < 4; ++mi)
        #pragma unroll
        for (int ni = 0; ni < 4; ++ni)
          acc[mi][ni] = __builtin_amdgcn_mfma_f32_16x16x32_bf16(af[mi], bfr[ni], acc[mi][ni], 0, 0, 0);
    }
    __syncthreads();
  }

  // epilogue: C/D layout col=lane&15, row=quad*4+reg (m89-verified)
  #pragma unroll
  for (int ni = 0; ni < 4; ++ni) {
    const int col = n0 + wn * 64 + ni * 16 + lr;
    const float bv = bias ? bias[col] : 0.f;
    #pragma unroll
    for (int mi = 0; mi < 4; ++mi) {
      const int rowb = m0 + wm * 64 + mi * 16 + lq * 4;
      #pragma unroll
      for (int i = 0; i < 4; ++i) {
        float v = acc[mi][ni][i] + bv;
        if (GELU) v = 0.5f * v * (1.0f + erff(v * 0.70710678118654752f));
        if (RESID == 1) v += ((const float*)Rv)[(size_t)(rowb + i) * ldr + col];
        if (RESID == 2) v += __bfloat162float(((const bf16*)Rv)[(size_t)(rowb + i) * ldr + col]);
        C[(size_t)(rowb + i) * ldc + col] = __float2bfloat16(v);
      }
    }
  }
}

// ---------------------------------------------------------------------------
// Window-5 causal attention, IN-PLACE into the q-columns of qkv.
// One wave per (token, head); lane = dim (hd=64). qkv row: [q(1024)|k|v].
// ---------------------------------------------------------------------------
__global__ __launch_bounds__(256) void attn_win(bf16* __restrict__ qkv)
{
  const int wid  = blockIdx.x * 4 + (threadIdx.x >> 6);
  const int lane = threadIdx.x & 63;
  const int h    = wid & 15;
  const int tk   = wid >> 4;        // flat token 0..4095
  const int s    = tk & 2047;       // position within sequence (S=2048)

  const size_t base = (size_t)tk * 3072;
  const float q = __bfloat162float(qkv[base + h * 64 + lane]);

  const int W = (s + 1 < 5) ? (s + 1) : 5;
  float sc[5];
  for (int wj = 0; wj < W; ++wj) {
    const int off = W - 1 - wj;                     // key index j = s - off
    const size_t kb = base - (size_t)off * 3072 + 1024 + h * 64;
    float p = q * __bfloat162float(qkv[kb + lane]);
    #pragma unroll
    for (int d = 1; d < 64; d <<= 1) p += __shfl_xor(p, d);
    sc[wj] = p * 0.125f;                            // 1/sqrt(64)
  }
  float mx = sc[0];
  for (int wj = 1; wj < W; ++wj) mx = fmaxf(mx, sc[wj]);
  float pr[5], sum = 0.f;
  for (int wj = 0; wj < W; ++wj) { pr[wj] = expf(sc[wj] - mx); sum += pr[wj]; }
  const float inv = 1.f / sum;
  float o = 0.f;
  for (int wj = 0; wj < W; ++wj) {
    const int off = W - 1 - wj;
    const size_t vb = base - (size_t)off * 3072 + 2048 + h * 64;
    o += pr[wj] * __bfloat162float(qkv[vb + lane]);
  }
  qkv[base + h * 64 + lane] = __float2bfloat16(o * inv);
}

// ---------------------------------------------------------------------------
// Fused split-K reduce + residual + bias + LayerNorm over dim=1024:
//   t = P0[r] + P1[r] + resid[r] + bias, then LN(t)*g + b.
// P0/P1 bf16 with row stride ldp; resid fp32 (RESBF16=0) or bf16 (1);
// out fp32 (OUTF32=1) or bf16 (0). One wave per token.
// ---------------------------------------------------------------------------
template<int OUTF32, int RESBF16>
__global__ __launch_bounds__(256) void ln_fuse(
    const bf16* __restrict__ P0, const bf16* __restrict__ P1, int ldp,
    const void* __restrict__ Rv,
    const float* __restrict__ bias,
    const float* __restrict__ g, const float* __restrict__ bt,
    void* __restrict__ outv)
{
  const int tk   = blockIdx.x * 4 + (threadIdx.x >> 6);
  const int lane = threadIdx.x & 63;
  const size_t bp = (size_t)tk * ldp;
  const size_t bo = (size_t)tk * 1024;

  float v[16];
  float sum = 0.f;
  #pragma unroll
  for (int i = 0; i < 16; ++i) {
    const int e = i * 64 + lane;
    float t = __bfloat162float(P0[bp + e]) + __bfloat162float(P1[bp + e]) + bias[e];
    if (RESBF16) t += __bfloat162float(((const bf16*)Rv)[bo + e]);
    else         t += ((const float*)Rv)[bo + e];
    v[i] = t;
    sum += t;
  }
  #pragma unroll
  for (int d = 1; d < 64; d <<= 1) sum += __shfl_xor(sum, d);
  const float mu = sum * (1.f / 1024.f);

  float sq = 0.f;
  #pragma unroll
  for (int i = 0; i < 16; ++i) { const float dv = v[i] - mu; sq += dv * dv; }
  #pragma unroll
  for (int d = 1; d < 64; d <<= 1) sq += __shfl_xor(sq, d);
  const float rstd = rsqrtf(sq * (1.f / 1024.f) + 1e-5f);

  #pragma unroll
  for (int i = 0; i < 16; ++i) {
    const int e = i * 64 + lane;
    const float o = (v[i] - mu) * rstd * g[e] + bt[e];
    if (OUTF32) ((float*)outv)[bo + e] = o;
    else        ((bf16*)outv)[bo + e] = __float2bfloat16(o);
  }
}

// ---------------------------------------------------------------------------
// WS layout (72 MB):
//   0        : qkv [4096,3072] bf16 (25.2) / phase2: h [4096,4096] (33.5)
//   33554432 : x_b [4096,1024] (GEMM1 A; dead after -> GEMM6 partial P0)
//   41943040 : x1_b [4096,1024] (live to end)
//   50331648 : w1_b [4096,1024] (GEMM5 B; dead after -> GEMM6 partial P1)
//   58720256 : w2_b [1024,4096]
//   67108864 : w_in_b [3072,1024]
//   73400320 : w_out_b [1024,1024]   (end 75497472)
// GEMM3 split-K partials go into the dead k-cols / v-cols of qkv.
// ---------------------------------------------------------------------------
extern "C" void kernel_launch(void* const* d_in, const int* in_sizes, int n_in,
                              void* d_out, int out_size, void* d_ws, size_t ws_size,
                              hipStream_t stream)
{
  const float* x     = (const float*)d_in[0];
  const float* w_in  = (const float*)d_in[1];
  const float* b_in  = (const float*)d_in[2];
  const float* w_out = (const float*)d_in[3];
  const float* b_out = (const float*)d_in[4];
  const float* ln1_g = (const float*)d_in[5];
  const float* ln1_b = (const float*)d_in[6];
  const float* ln2_g = (const float*)d_in[7];
  const float* ln2_b = (const float*)d_in[8];
  const float* w1    = (const float*)d_in[9];
  const float* b1    = (const float*)d_in[10];
  const float* w2    = (const float*)d_in[11];
  const float* b2    = (const float*)d_in[12];
  float* out = (float*)d_out;

  char* ws = (char*)d_ws;
  bf16* qkv     = (bf16*)(ws);
  bf16* h       = (bf16*)(ws);
  bf16* x_b     = (bf16*)(ws + 33554432);
  bf16* x1_b    = (bf16*)(ws + 41943040);
  bf16* w1_b    = (bf16*)(ws + 50331648);
  bf16* w2_b    = (bf16*)(ws + 58720256);
  bf16* w_in_b  = (bf16*)(ws + 67108864);
  bf16* w_out_b = (bf16*)(ws + 73400320);
  bf16* P0      = x_b;               // GEMM6 partials (regions dead by then)
  bf16* P1      = w1_b;

  const dim3 blk(256);

  // 0) fp32 -> bf16 operand conversion
  cvt_f32_bf16<<<dim3(4096), blk, 0, stream>>>(x,     x_b,     4194304);
  cvt_f32_bf16<<<dim3(3072), blk, 0, stream>>>(w_in,  w_in_b,  3145728);
  cvt_f32_bf16<<<dim3(1024), blk, 0, stream>>>(w_out, w_out_b, 1048576);
  cvt_f32_bf16<<<dim3(4096), blk, 0, stream>>>(w1,    w1_b,    4194304);
  cvt_f32_bf16<<<dim3(4096), blk, 0, stream>>>(w2,    w2_b,    4194304);

  // 1) qkv = x @ w_in^T + b_in                      [4096,3072], grid 768
  gemm_bt<0,0><<<dim3(24, 32, 1), blk, 0, stream>>>(
      x_b, 1024, w_in_b, 1024, b_in, nullptr, 0, qkv, 3072, 0, 4096, 3072, 1024);
  // 2) windowed causal attention, in-place into q-cols
  attn_win<<<dim3(16384), blk, 0, stream>>>(qkv);
  // 3) split-K=2: k-cols/v-cols = attn @ w_out^T partials   grid 512
  gemm_bt<0,0><<<dim3(8, 32, 2), blk, 0, stream>>>(
      qkv, 3072, w_out_b, 1024, nullptr, nullptr, 0,
      qkv + 1024, 3072, 1024, 4096, 1024, 512);
  // 4) x1_b = LN(x + P0 + P1 + b_out)
  ln_fuse<0,0><<<dim3(1024), blk, 0, stream>>>(
      qkv + 1024, qkv + 2048, 3072, x, b_out, ln1_g, ln1_b, x1_b);
  // 5) h = gelu(x1 @ w1^T + b1)                     [4096,4096], grid 1024
  gemm_bt<1,0><<<dim3(32, 32, 1), blk, 0, stream>>>(
      x1_b, 1024, w1_b, 1024, b1, nullptr, 0, h, 4096, 0, 4096, 4096, 1024);
  // 6) split-K=2: P0/P1 = h @ w2^T partials          grid 512
  gemm_bt<0,0><<<dim3(8, 32, 2), blk, 0, stream>>>(
      h, 4096, w2_b, 4096, nullptr, nullptr, 0,
      P0, 1024, 8388608, 4096, 1024, 2048);
  // 7) out(fp32) = LN(x1 + P0 + P1 + b2)
  ln_fuse<1,1><<<dim3(1024), blk, 0, stream>>>(
      P0, P1, 1024, x1_b, b2, ln2_g, ln2_b, out);
}

// Round 5
// 317.585 us; speedup vs baseline: 1.3176x; 1.1054x over previous
//
#include <hip/hip_runtime.h>
#include <hip/hip_bf16.h>
#include <math.h>

typedef __hip_bfloat16 bf16;
typedef __attribute__((ext_vector_type(8))) short bf16x8;
typedef __attribute__((ext_vector_type(4))) float f32x4;

#define GPTR(p) ((const __attribute__((address_space(1))) void*)(p))
#define LPTR(p) ((__attribute__((address_space(3))) void*)(p))

// ---------------------------------------------------------------------------
// Merged fp32 -> bf16 conversion for all 5 MFMA operand tensors (1 dispatch).
// Segment sizes in 256-thread x 4-elem blocks: x 4096 | w_in 3072 | w_out 1024
// | w1 4096 | w2 4096  (total 16384 blocks, every segment exactly divisible).
// ---------------------------------------------------------------------------
__global__ __launch_bounds__(256) void cvt_all(
    const float* __restrict__ x,    const float* __restrict__ w_in,
    const float* __restrict__ w_out,const float* __restrict__ w1,
    const float* __restrict__ w2,
    bf16* __restrict__ xb,   bf16* __restrict__ winb, bf16* __restrict__ woutb,
    bf16* __restrict__ w1b,  bf16* __restrict__ w2b)
{
  const int b = blockIdx.x;
  const float* in; bf16* out; int base;
  if      (b <  4096) { in = x;     out = xb;    base = 0; }
  else if (b <  7168) { in = w_in;  out = winb;  base = 4096; }
  else if (b <  8192) { in = w_out; out = woutb; base = 7168; }
  else if (b < 12288) { in = w1;    out = w1b;   base = 8192; }
  else                { in = w2;    out = w2b;   base = 12288; }
  const int i = ((b - base) * 256 + threadIdx.x) * 4;
  const float4 f = *(const float4*)(in + i);
  ushort4 u;
  u.x = __bfloat16_as_ushort(__float2bfloat16(f.x));
  u.y = __bfloat16_as_ushort(__float2bfloat16(f.y));
  u.z = __bfloat16_as_ushort(__float2bfloat16(f.z));
  u.w = __bfloat16_as_ushort(__float2bfloat16(f.w));
  *(ushort4*)(out + i) = u;
}

__device__ __forceinline__ float gelu_fast(float v) {
  // tanh-form GELU via hw exp: |err vs erf-form| <= ~3e-3 (margin 0.077)
  const float u  = 1.5957691216f * (v + 0.044715f * v * v * v);  // 2*0.7978845608
  const float e  = __expf(u);
  return v * e / (e + 1.0f);   // 0.5v(1+tanh(u/2)) == v*e^u/(e^u+1)
}

// ---------------------------------------------------------------------------
// GEMM: C[M,N](bf16) = A[M,K](lda) * B[N,K]^T(ldb) [+ bias(fp32)] with
// optional fast-GELU / residual epilogue and split-K via blockIdx.z.
// 128x128 tile, BK=64, 4 waves (2x2), 4x4 mfma_f32_16x16x32_bf16 per wave.
// XOR chunk swizzle keeps fragment ds_read_b128 at 2-way conflicts (free).
// __launch_bounds__(256,4): cap unified regs at 128 (64 AGPR + <=64 VGPR)
// -> 4 blocks/CU (was 148 regs -> 2 blocks/CU, OccupancyPercent 22%).
// ---------------------------------------------------------------------------
template<int GELU, int RESID>   // RESID: 0 none, 1 fp32, 2 bf16
__global__ __launch_bounds__(256, 4) void gemm_bt(
    const bf16* __restrict__ A, int lda,
    const bf16* __restrict__ B, int ldb,
    const float* __restrict__ bias,
    const void* __restrict__ Rv, int ldr,
    bf16* __restrict__ C, int ldc, long czstride,
    int M, int N, int kchunk)
{
  __shared__ __align__(16) bf16 As[128 * 64];
  __shared__ __align__(16) bf16 Bs[128 * 64];

  const int t    = threadIdx.x;
  const int lane = t & 63;
  const int w    = t >> 6;
  const int wm   = w >> 1;
  const int wn   = w & 1;
  const int lr   = lane & 15;       // fragment row (A) / col (B,C)
  const int lq   = lane >> 4;       // quad 0..3
  const int m0   = blockIdx.y * 128;
  const int n0   = blockIdx.x * 128;
  const int kz   = blockIdx.z;

  A += (size_t)kz * kchunk;
  B += (size_t)kz * kchunk;
  C += (size_t)kz * czstride;

  f32x4 acc[4][4];
  #pragma unroll
  for (int mi = 0; mi < 4; ++mi)
    #pragma unroll
    for (int ni = 0; ni < 4; ++ni)
      acc[mi][ni] = (f32x4){0.f, 0.f, 0.f, 0.f};

  const int wbase = (t & ~63) * 8;  // wave-uniform LDS element base

  for (int k0 = 0; k0 < kchunk; k0 += 64) {
    #pragma unroll
    for (int it = 0; it < 4; ++it) {
      const int c    = it * 256 + t;
      const int row  = c >> 3;
      const int csw  = ((c & 7) ^ (row & 7)) << 3;   // swizzled source chunk
      const bf16* ga = A + (size_t)(m0 + row) * lda + k0 + csw;
      const bf16* gb = B + (size_t)(n0 + row) * ldb + k0 + csw;
      __builtin_amdgcn_global_load_lds(GPTR(ga), LPTR(&As[it * 2048 + wbase]), 16, 0, 0);
      __builtin_amdgcn_global_load_lds(GPTR(gb), LPTR(&Bs[it * 2048 + wbase]), 16, 0, 0);
    }
    __syncthreads();

    #pragma unroll
    for (int ks = 0; ks < 2; ++ks) {
      const int swz = (((ks * 4 + lq) ^ (lr & 7)) << 3);  // swizzled read chunk
      bf16x8 af[4], bfr[4];
      #pragma unroll
      for (int mi = 0; mi < 4; ++mi)
        af[mi] = *(const bf16x8*)&As[(wm * 64 + mi * 16 + lr) * 64 + swz];
      #pragma unroll
      for (int ni = 0; ni < 4; ++ni)
        bfr[ni] = *(const bf16x8*)&Bs[(wn * 64 + ni * 16 + lr) * 64 + swz];
      #pragma unroll
      for (int mi = 0; mi < 4; ++mi)
        #pragma unroll
        for (int ni = 0; ni < 4; ++ni)
          acc[mi][ni] = __builtin_amdgcn_mfma_f32_16x16x32_bf16(af[mi], bfr[ni], acc[mi][ni], 0, 0, 0);
    }
    __syncthreads();
  }

  // epilogue: C/D layout col=lane&15, row=quad*4+reg (m89-verified)
  #pragma unroll
  for (int ni = 0; ni < 4; ++ni) {
    const int col = n0 + wn * 64 + ni * 16 + lr;
    const float bv = bias ? bias[col] : 0.f;
    #pragma unroll
    for (int mi = 0; mi < 4; ++mi) {
      const int rowb = m0 + wm * 64 + mi * 16 + lq * 4;
      #pragma unroll
      for (int i = 0; i < 4; ++i) {
        float v = acc[mi][ni][i] + bv;
        if (GELU) v = gelu_fast(v);
        if (RESID == 1) v += ((const float*)Rv)[(size_t)(rowb + i) * ldr + col];
        if (RESID == 2) v += __bfloat162float(((const bf16*)Rv)[(size_t)(rowb + i) * ldr + col]);
        C[(size_t)(rowb + i) * ldc + col] = __float2bfloat16(v);
      }
    }
  }
}

// ---------------------------------------------------------------------------
// Window-5 causal attention, IN-PLACE into the q-columns of qkv.
// One wave per (token, head); lane = dim (hd=64). qkv row: [q(1024)|k|v].
// ---------------------------------------------------------------------------
__global__ __launch_bounds__(256) void attn_win(bf16* __restrict__ qkv)
{
  const int wid  = blockIdx.x * 4 + (threadIdx.x >> 6);
  const int lane = threadIdx.x & 63;
  const int h    = wid & 15;
  const int tk   = wid >> 4;        // flat token 0..4095
  const int s    = tk & 2047;       // position within sequence (S=2048)

  const size_t base = (size_t)tk * 3072;
  const float q = __bfloat162float(qkv[base + h * 64 + lane]);

  const int W = (s + 1 < 5) ? (s + 1) : 5;
  float sc[5];
  for (int wj = 0; wj < W; ++wj) {
    const int off = W - 1 - wj;                     // key index j = s - off
    const size_t kb = base - (size_t)off * 3072 + 1024 + h * 64;
    float p = q * __bfloat162float(qkv[kb + lane]);
    #pragma unroll
    for (int d = 1; d < 64; d <<= 1) p += __shfl_xor(p, d);
    sc[wj] = p * 0.125f;                            // 1/sqrt(64)
  }
  float mx = sc[0];
  for (int wj = 1; wj < W; ++wj) mx = fmaxf(mx, sc[wj]);
  float pr[5], sum = 0.f;
  for (int wj = 0; wj < W; ++wj) { pr[wj] = expf(sc[wj] - mx); sum += pr[wj]; }
  const float inv = 1.f / sum;
  float o = 0.f;
  for (int wj = 0; wj < W; ++wj) {
    const int off = W - 1 - wj;
    const size_t vb = base - (size_t)off * 3072 + 2048 + h * 64;
    o += pr[wj] * __bfloat162float(qkv[vb + lane]);
  }
  qkv[base + h * 64 + lane] = __float2bfloat16(o * inv);
}

// ---------------------------------------------------------------------------
// Fused split-K reduce + residual + bias + LayerNorm over dim=1024:
//   t = P0[r] + P1[r] + resid[r] + bias, then LN(t)*g + b.
// ---------------------------------------------------------------------------
template<int OUTF32, int RESBF16>
__global__ __launch_bounds__(256) void ln_fuse(
    const bf16* __restrict__ P0, const bf16* __restrict__ P1, int ldp,
    const void* __restrict__ Rv,
    const float* __restrict__ bias,
    const float* __restrict__ g, const float* __restrict__ bt,
    void* __restrict__ outv)
{
  const int tk   = blockIdx.x * 4 + (threadIdx.x >> 6);
  const int lane = threadIdx.x & 63;
  const size_t bp = (size_t)tk * ldp;
  const size_t bo = (size_t)tk * 1024;

  float v[16];
  float sum = 0.f;
  #pragma unroll
  for (int i = 0; i < 16; ++i) {
    const int e = i * 64 + lane;
    float t = __bfloat162float(P0[bp + e]) + __bfloat162float(P1[bp + e]) + bias[e];
    if (RESBF16) t += __bfloat162float(((const bf16*)Rv)[bo + e]);
    else         t += ((const float*)Rv)[bo + e];
    v[i] = t;
    sum += t;
  }
  #pragma unroll
  for (int d = 1; d < 64; d <<= 1) sum += __shfl_xor(sum, d);
  const float mu = sum * (1.f / 1024.f);

  float sq = 0.f;
  #pragma unroll
  for (int i = 0; i < 16; ++i) { const float dv = v[i] - mu; sq += dv * dv; }
  #pragma unroll
  for (int d = 1; d < 64; d <<= 1) sq += __shfl_xor(sq, d);
  const float rstd = rsqrtf(sq * (1.f / 1024.f) + 1e-5f);

  #pragma unroll
  for (int i = 0; i < 16; ++i) {
    const int e = i * 64 + lane;
    const float o = (v[i] - mu) * rstd * g[e] + bt[e];
    if (OUTF32) ((float*)outv)[bo + e] = o;
    else        ((bf16*)outv)[bo + e] = __float2bfloat16(o);
  }
}

// ---------------------------------------------------------------------------
// WS layout (72 MB):
//   0        : qkv [4096,3072] bf16 (25.2) / phase2: h [4096,4096] (33.5)
//   33554432 : x_b [4096,1024] (GEMM1 A; dead after -> GEMM6 partial P0)
//   41943040 : x1_b [4096,1024] (live to end)
//   50331648 : w1_b [4096,1024] (GEMM5 B; dead after -> GEMM6 partial P1)
//   58720256 : w2_b [1024,4096]
//   67108864 : w_in_b [3072,1024]
//   73400320 : w_out_b [1024,1024]   (end 75497472)
// ---------------------------------------------------------------------------
extern "C" void kernel_launch(void* const* d_in, const int* in_sizes, int n_in,
                              void* d_out, int out_size, void* d_ws, size_t ws_size,
                              hipStream_t stream)
{
  const float* x     = (const float*)d_in[0];
  const float* w_in  = (const float*)d_in[1];
  const float* b_in  = (const float*)d_in[2];
  const float* w_out = (const float*)d_in[3];
  const float* b_out = (const float*)d_in[4];
  const float* ln1_g = (const float*)d_in[5];
  const float* ln1_b = (const float*)d_in[6];
  const float* ln2_g = (const float*)d_in[7];
  const float* ln2_b = (const float*)d_in[8];
  const float* w1    = (const float*)d_in[9];
  const float* b1    = (const float*)d_in[10];
  const float* w2    = (const float*)d_in[11];
  const float* b2    = (const float*)d_in[12];
  float* out = (float*)d_out;

  char* ws = (char*)d_ws;
  bf16* qkv     = (bf16*)(ws);
  bf16* h       = (bf16*)(ws);
  bf16* x_b     = (bf16*)(ws + 33554432);
  bf16* x1_b    = (bf16*)(ws + 41943040);
  bf16* w1_b    = (bf16*)(ws + 50331648);
  bf16* w2_b    = (bf16*)(ws + 58720256);
  bf16* w_in_b  = (bf16*)(ws + 67108864);
  bf16* w_out_b = (bf16*)(ws + 73400320);
  bf16* P0      = x_b;               // GEMM6 partials (regions dead by then)
  bf16* P1      = w1_b;

  const dim3 blk(256);

  // 0) fp32 -> bf16 operand conversion (single dispatch)
  cvt_all<<<dim3(16384), blk, 0, stream>>>(x, w_in, w_out, w1, w2,
                                           x_b, w_in_b, w_out_b, w1_b, w2_b);

  // 1) qkv = x @ w_in^T + b_in                      [4096,3072], grid 768
  gemm_bt<0,0><<<dim3(24, 32, 1), blk, 0, stream>>>(
      x_b, 1024, w_in_b, 1024, b_in, nullptr, 0, qkv, 3072, 0, 4096, 3072, 1024);
  // 2) windowed causal attention, in-place into q-cols
  attn_win<<<dim3(16384), blk, 0, stream>>>(qkv);
  // 3) split-K=2: k-cols/v-cols = attn @ w_out^T partials   grid 512
  gemm_bt<0,0><<<dim3(8, 32, 2), blk, 0, stream>>>(
      qkv, 3072, w_out_b, 1024, nullptr, nullptr, 0,
      qkv + 1024, 3072, 1024, 4096, 1024, 512);
  // 4) x1_b = LN(x + P0 + P1 + b_out)
  ln_fuse<0,0><<<dim3(1024), blk, 0, stream>>>(
      qkv + 1024, qkv + 2048, 3072, x, b_out, ln1_g, ln1_b, x1_b);
  // 5) h = gelu(x1 @ w1^T + b1)                     [4096,4096], grid 1024
  gemm_bt<1,0><<<dim3(32, 32, 1), blk, 0, stream>>>(
      x1_b, 1024, w1_b, 1024, b1, nullptr, 0, h, 4096, 0, 4096, 4096, 1024);
  // 6) split-K=2: P0/P1 = h @ w2^T partials          grid 512
  gemm_bt<0,0><<<dim3(8, 32, 2), blk, 0, stream>>>(
      h, 4096, w2_b, 4096, nullptr, nullptr, 0,
      P0, 1024, 8388608, 4096, 1024, 2048);
  // 7) out(fp32) = LN(x1 + P0 + P1 + b2)
  ln_fuse<1,1><<<dim3(1024), blk, 0, stream>>>(
      P0, P1, 1024, x1_b, b2, ln2_g, ln2_b, out);
}

// Round 6
// 274.813 us; speedup vs baseline: 1.5227x; 1.1556x over previous
//
#include <hip/hip_runtime.h>
#include <hip/hip_bf16.h>
#include <math.h>

typedef __hip_bfloat16 bf16;
typedef __attribute__((ext_vector_type(8))) short bf16x8;
typedef __attribute__((ext_vector_type(4))) float f32x4;

#define GPTR(p) ((const __attribute__((address_space(1))) void*)(p))
#define LPTR(p) ((__attribute__((address_space(3))) void*)(p))

__device__ __forceinline__ float b2f(short s) {
  unsigned int u = ((unsigned int)(unsigned short)s) << 16;
  float f; __builtin_memcpy(&f, &u, 4); return f;
}

// ---------------------------------------------------------------------------
// Merged fp32 -> bf16 conversion for all 5 MFMA operand tensors (1 dispatch).
// ---------------------------------------------------------------------------
__global__ __launch_bounds__(256) void cvt_all(
    const float* __restrict__ x,    const float* __restrict__ w_in,
    const float* __restrict__ w_out,const float* __restrict__ w1,
    const float* __restrict__ w2,
    bf16* __restrict__ xb,   bf16* __restrict__ winb, bf16* __restrict__ woutb,
    bf16* __restrict__ w1b,  bf16* __restrict__ w2b)
{
  const int b = blockIdx.x;
  const float* in; bf16* out; int base;
  if      (b <  4096) { in = x;     out = xb;    base = 0; }
  else if (b <  7168) { in = w_in;  out = winb;  base = 4096; }
  else if (b <  8192) { in = w_out; out = woutb; base = 7168; }
  else if (b < 12288) { in = w1;    out = w1b;   base = 8192; }
  else                { in = w2;    out = w2b;   base = 12288; }
  const int i = ((b - base) * 256 + threadIdx.x) * 4;
  const float4 f = *(const float4*)(in + i);
  ushort4 u;
  u.x = __bfloat16_as_ushort(__float2bfloat16(f.x));
  u.y = __bfloat16_as_ushort(__float2bfloat16(f.y));
  u.z = __bfloat16_as_ushort(__float2bfloat16(f.z));
  u.w = __bfloat16_as_ushort(__float2bfloat16(f.w));
  *(ushort4*)(out + i) = u;
}

__device__ __forceinline__ float gelu_fast(float v) {
  const float u  = 1.5957691216f * (v + 0.044715f * v * v * v);
  const float e  = __expf(u);
  return v * e / (e + 1.0f);
}

// ---------------------------------------------------------------------------
// GEMM: C[M,N](bf16) = A[M,K](lda) * B[N,K]^T(ldb) [+ bias(fp32)] with
// optional fast-GELU / residual epilogue and split-K via blockIdx.z.
// 128x128 tile, BK=64, 4 waves (2x2), 4x4 mfma_f32_16x16x32_bf16 per wave.
// XOR chunk swizzle -> 2-way LDS conflicts (free). __launch_bounds__(256,4)
// caps unified regs at 128 -> 4 blocks/CU.
// ---------------------------------------------------------------------------
template<int GELU, int RESID>   // RESID: 0 none, 1 fp32, 2 bf16
__global__ __launch_bounds__(256, 4) void gemm_bt(
    const bf16* __restrict__ A, int lda,
    const bf16* __restrict__ B, int ldb,
    const float* __restrict__ bias,
    const void* __restrict__ Rv, int ldr,
    bf16* __restrict__ C, int ldc, long czstride,
    int M, int N, int kchunk)
{
  __shared__ __align__(16) bf16 As[128 * 64];
  __shared__ __align__(16) bf16 Bs[128 * 64];

  const int t    = threadIdx.x;
  const int lane = t & 63;
  const int w    = t >> 6;
  const int wm   = w >> 1;
  const int wn   = w & 1;
  const int lr   = lane & 15;
  const int lq   = lane >> 4;
  const int m0   = blockIdx.y * 128;
  const int n0   = blockIdx.x * 128;
  const int kz   = blockIdx.z;

  A += (size_t)kz * kchunk;
  B += (size_t)kz * kchunk;
  C += (size_t)kz * czstride;

  f32x4 acc[4][4];
  #pragma unroll
  for (int mi = 0; mi < 4; ++mi)
    #pragma unroll
    for (int ni = 0; ni < 4; ++ni)
      acc[mi][ni] = (f32x4){0.f, 0.f, 0.f, 0.f};

  const int wbase = (t & ~63) * 8;

  for (int k0 = 0; k0 < kchunk; k0 += 64) {
    #pragma unroll
    for (int it = 0; it < 4; ++it) {
      const int c    = it * 256 + t;
      const int row  = c >> 3;
      const int csw  = ((c & 7) ^ (row & 7)) << 3;
      const bf16* ga = A + (size_t)(m0 + row) * lda + k0 + csw;
      const bf16* gb = B + (size_t)(n0 + row) * ldb + k0 + csw;
      __builtin_amdgcn_global_load_lds(GPTR(ga), LPTR(&As[it * 2048 + wbase]), 16, 0, 0);
      __builtin_amdgcn_global_load_lds(GPTR(gb), LPTR(&Bs[it * 2048 + wbase]), 16, 0, 0);
    }
    __syncthreads();

    #pragma unroll
    for (int ks = 0; ks < 2; ++ks) {
      const int swz = (((ks * 4 + lq) ^ (lr & 7)) << 3);
      bf16x8 af[4], bfr[4];
      #pragma unroll
      for (int mi = 0; mi < 4; ++mi)
        af[mi] = *(const bf16x8*)&As[(wm * 64 + mi * 16 + lr) * 64 + swz];
      #pragma unroll
      for (int ni = 0; ni < 4; ++ni)
        bfr[ni] = *(const bf16x8*)&Bs[(wn * 64 + ni * 16 + lr) * 64 + swz];
      #pragma unroll
      for (int mi = 0; mi < 4; ++mi)
        #pragma unroll
        for (int ni = 0; ni < 4; ++ni)
          acc[mi][ni] = __builtin_amdgcn_mfma_f32_16x16x32_bf16(af[mi], bfr[ni], acc[mi][ni], 0, 0, 0);
    }
    __syncthreads();
  }

  #pragma unroll
  for (int ni = 0; ni < 4; ++ni) {
    const int col = n0 + wn * 64 + ni * 16 + lr;
    const float bv = bias ? bias[col] : 0.f;
    #pragma unroll
    for (int mi = 0; mi < 4; ++mi) {
      const int rowb = m0 + wm * 64 + mi * 16 + lq * 4;
      #pragma unroll
      for (int i = 0; i < 4; ++i) {
        float v = acc[mi][ni][i] + bv;
        if (GELU) v = gelu_fast(v);
        if (RESID == 1) v += ((const float*)Rv)[(size_t)(rowb + i) * ldr + col];
        if (RESID == 2) v += __bfloat162float(((const bf16*)Rv)[(size_t)(rowb + i) * ldr + col]);
        C[(size_t)(rowb + i) * ldc + col] = __float2bfloat16(v);
      }
    }
  }
}

// ---------------------------------------------------------------------------
// Window-5 causal attention, one WAVE per token (replaces wave-per-(t,h)
// with 30 butterfly shuffles: was 56 us, VALUBusy 78%, hbm 6.5%).
// lane = h*4 + c: head h (0..15), chunk c (0..3) of 16 dims. Per wave:
// q row read once (coalesced 16B/lane), per window j: k row 2 vec loads,
// 16 fp32 FMAs, 2 shuffles (reduce over 4 lanes); scores stay in registers
// per lane -> softmax register-local; output = 5 v-row vec loads + FMAs.
// In-place into q-cols (wave t is the sole reader of q[t]).
// ---------------------------------------------------------------------------
__global__ __launch_bounds__(256) void attn_win(bf16* __restrict__ qkv)
{
  const int lane = threadIdx.x & 63;
  const int tk   = blockIdx.x * 4 + (threadIdx.x >> 6);   // token 0..4095
  const int s    = tk & 2047;                             // pos in sequence
  const int doff = (lane >> 2) * 64 + (lane & 3) * 16;    // h*64 + c*16

  const size_t row = (size_t)tk * 3072;

  // q fragment -> fp32 registers
  bf16x8 qa = *(const bf16x8*)&qkv[row + doff];
  bf16x8 qb = *(const bf16x8*)&qkv[row + doff + 8];
  float qf[16];
  #pragma unroll
  for (int e = 0; e < 8; ++e) { qf[e] = b2f(qa[e]); qf[8 + e] = b2f(qb[e]); }

  const int W = (s + 1 < 5) ? (s + 1) : 5;
  float p[5];
  #pragma unroll
  for (int j = 0; j < 5; ++j) {
    const int jc = (j < W) ? j : 0;                       // clamped (valid addr)
    const size_t kr = row - (size_t)jc * 3072 + 1024;
    bf16x8 ka = *(const bf16x8*)&qkv[kr + doff];
    bf16x8 kb = *(const bf16x8*)&qkv[kr + doff + 8];
    float d = 0.f;
    #pragma unroll
    for (int e = 0; e < 8; ++e) d += qf[e] * b2f(ka[e]);
    #pragma unroll
    for (int e = 0; e < 8; ++e) d += qf[8 + e] * b2f(kb[e]);
    d += __shfl_xor(d, 1);
    d += __shfl_xor(d, 2);
    p[j] = (j < W) ? d * 0.125f : -1e30f;                 // 1/sqrt(64); mask
  }

  float mx = fmaxf(fmaxf(fmaxf(p[0], p[1]), fmaxf(p[2], p[3])), p[4]);
  float sum = 0.f;
  #pragma unroll
  for (int j = 0; j < 5; ++j) { p[j] = __expf(p[j] - mx); sum += p[j]; }
  const float inv = 1.f / sum;

  float o[16];
  #pragma unroll
  for (int e = 0; e < 16; ++e) o[e] = 0.f;
  #pragma unroll
  for (int j = 0; j < 5; ++j) {
    const int jc = (j < W) ? j : 0;
    const size_t vr = row - (size_t)jc * 3072 + 2048;
    bf16x8 va = *(const bf16x8*)&qkv[vr + doff];
    bf16x8 vb = *(const bf16x8*)&qkv[vr + doff + 8];
    #pragma unroll
    for (int e = 0; e < 8; ++e) { o[e] += p[j] * b2f(va[e]); o[8 + e] += p[j] * b2f(vb[e]); }
  }

  bf16x8 oa, ob;
  #pragma unroll
  for (int e = 0; e < 8; ++e) {
    oa[e] = (short)__bfloat16_as_ushort(__float2bfloat16(o[e] * inv));
    ob[e] = (short)__bfloat16_as_ushort(__float2bfloat16(o[8 + e] * inv));
  }
  *(bf16x8*)&qkv[row + doff]     = oa;
  *(bf16x8*)&qkv[row + doff + 8] = ob;
}

// ---------------------------------------------------------------------------
// Fused split-K reduce + residual + bias + LayerNorm over dim=1024.
// ---------------------------------------------------------------------------
template<int OUTF32, int RESBF16>
__global__ __launch_bounds__(256) void ln_fuse(
    const bf16* __restrict__ P0, const bf16* __restrict__ P1, int ldp,
    const void* __restrict__ Rv,
    const float* __restrict__ bias,
    const float* __restrict__ g, const float* __restrict__ bt,
    void* __restrict__ outv)
{
  const int tk   = blockIdx.x * 4 + (threadIdx.x >> 6);
  const int lane = threadIdx.x & 63;
  const size_t bp = (size_t)tk * ldp;
  const size_t bo = (size_t)tk * 1024;

  float v[16];
  float sum = 0.f;
  #pragma unroll
  for (int i = 0; i < 16; ++i) {
    const int e = i * 64 + lane;
    float t = __bfloat162float(P0[bp + e]) + __bfloat162float(P1[bp + e]) + bias[e];
    if (RESBF16) t += __bfloat162float(((const bf16*)Rv)[bo + e]);
    else         t += ((const float*)Rv)[bo + e];
    v[i] = t;
    sum += t;
  }
  #pragma unroll
  for (int d = 1; d < 64; d <<= 1) sum += __shfl_xor(sum, d);
  const float mu = sum * (1.f / 1024.f);

  float sq = 0.f;
  #pragma unroll
  for (int i = 0; i < 16; ++i) { const float dv = v[i] - mu; sq += dv * dv; }
  #pragma unroll
  for (int d = 1; d < 64; d <<= 1) sq += __shfl_xor(sq, d);
  const float rstd = rsqrtf(sq * (1.f / 1024.f) + 1e-5f);

  #pragma unroll
  for (int i = 0; i < 16; ++i) {
    const int e = i * 64 + lane;
    const float o = (v[i] - mu) * rstd * g[e] + bt[e];
    if (OUTF32) ((float*)outv)[bo + e] = o;
    else        ((bf16*)outv)[bo + e] = __float2bfloat16(o);
  }
}

// ---------------------------------------------------------------------------
// WS layout (72 MB):
//   0        : qkv [4096,3072] bf16 / phase2: h [4096,4096]
//   33554432 : x_b [4096,1024] -> GEMM6 partial P0
//   41943040 : x1_b [4096,1024]
//   50331648 : w1_b [4096,1024] -> GEMM6 partial P1
//   58720256 : w2_b [1024,4096]
//   67108864 : w_in_b [3072,1024]
//   73400320 : w_out_b [1024,1024]
// ---------------------------------------------------------------------------
extern "C" void kernel_launch(void* const* d_in, const int* in_sizes, int n_in,
                              void* d_out, int out_size, void* d_ws, size_t ws_size,
                              hipStream_t stream)
{
  const float* x     = (const float*)d_in[0];
  const float* w_in  = (const float*)d_in[1];
  const float* b_in  = (const float*)d_in[2];
  const float* w_out = (const float*)d_in[3];
  const float* b_out = (const float*)d_in[4];
  const float* ln1_g = (const float*)d_in[5];
  const float* ln1_b = (const float*)d_in[6];
  const float* ln2_g = (const float*)d_in[7];
  const float* ln2_b = (const float*)d_in[8];
  const float* w1    = (const float*)d_in[9];
  const float* b1    = (const float*)d_in[10];
  const float* w2    = (const float*)d_in[11];
  const float* b2    = (const float*)d_in[12];
  float* out = (float*)d_out;

  char* ws = (char*)d_ws;
  bf16* qkv     = (bf16*)(ws);
  bf16* h       = (bf16*)(ws);
  bf16* x_b     = (bf16*)(ws + 33554432);
  bf16* x1_b    = (bf16*)(ws + 41943040);
  bf16* w1_b    = (bf16*)(ws + 50331648);
  bf16* w2_b    = (bf16*)(ws + 58720256);
  bf16* w_in_b  = (bf16*)(ws + 67108864);
  bf16* w_out_b = (bf16*)(ws + 73400320);
  bf16* P0      = x_b;
  bf16* P1      = w1_b;

  const dim3 blk(256);

  // 0) fp32 -> bf16 operand conversion (single dispatch)
  cvt_all<<<dim3(16384), blk, 0, stream>>>(x, w_in, w_out, w1, w2,
                                           x_b, w_in_b, w_out_b, w1_b, w2_b);

  // 1) qkv = x @ w_in^T + b_in                      [4096,3072]
  gemm_bt<0,0><<<dim3(24, 32, 1), blk, 0, stream>>>(
      x_b, 1024, w_in_b, 1024, b_in, nullptr, 0, qkv, 3072, 0, 4096, 3072, 1024);
  // 2) windowed causal attention, in-place into q-cols (wave per token)
  attn_win<<<dim3(1024), blk, 0, stream>>>(qkv);
  // 3) split-K=2: k-cols/v-cols = attn @ w_out^T partials
  gemm_bt<0,0><<<dim3(8, 32, 2), blk, 0, stream>>>(
      qkv, 3072, w_out_b, 1024, nullptr, nullptr, 0,
      qkv + 1024, 3072, 1024, 4096, 1024, 512);
  // 4) x1_b = LN(x + P0 + P1 + b_out)
  ln_fuse<0,0><<<dim3(1024), blk, 0, stream>>>(
      qkv + 1024, qkv + 2048, 3072, x, b_out, ln1_g, ln1_b, x1_b);
  // 5) h = gelu(x1 @ w1^T + b1)                     [4096,4096]
  gemm_bt<1,0><<<dim3(32, 32, 1), blk, 0, stream>>>(
      x1_b, 1024, w1_b, 1024, b1, nullptr, 0, h, 4096, 0, 4096, 4096, 1024);
  // 6) split-K=2: P0/P1 = h @ w2^T partials
  gemm_bt<0,0><<<dim3(8, 32, 2), blk, 0, stream>>>(
      h, 4096, w2_b, 4096, nullptr, nullptr, 0,
      P0, 1024, 8388608, 4096, 1024, 2048);
  // 7) out(fp32) = LN(x1 + P0 + P1 + b2)
  ln_fuse<1,1><<<dim3(1024), blk, 0, stream>>>(
      P0, P1, 1024, x1_b, b2, ln2_g, ln2_b, out);
}